// Round 22
// baseline (122.306 us; speedup 1.0000x reference)
//
#include <hip/hip_runtime.h>

#define N_NODES 20000
#define N_EDGES 160000
#define N_PAIRS 50000
#define DMAX 32
#define MB 32          // nodes per epi block (625 blocks -> 2.4 blocks/CU)
// F_IN = CHANNELS = 32, EDGE_DIM = 8; G row = 288 floats (knw 256 + knb 32)

__device__ __forceinline__ float4 f4fma(float s, float4 w, float4 a) {
    a.x += s * w.x; a.y += s * w.y; a.z += s * w.z; a.w += s * w.w;
    return a;
}

__device__ __forceinline__ float bf2f(unsigned int u) {  // low 16 bits = bf16
    return __uint_as_float(u << 16);
}
__device__ __forceinline__ unsigned int f2bf(float f) {  // RNE, low 16 bits
    unsigned int u = __float_as_uint(f);
    u += 0x7fffu + ((u >> 16) & 1u);
    return u >> 16;
}

__global__ void zero_cnt(int* __restrict__ c) {
    int t = blockIdx.x * blockDim.x + threadIdx.x;
    if (t < N_NODES) c[t] = 0;
}

// adjacency by target: slot -> src (int) + bf16-packed E row (uint4, 16B).
__global__ __launch_bounds__(256) void fill_adj(const int* __restrict__ ei,
                                                const float* __restrict__ E,
                                                int* __restrict__ cnt,
                                                int* __restrict__ adjsrc,
                                                uint4* __restrict__ adjEb) {
    int e = blockIdx.x * blockDim.x + threadIdx.x;
    if (e >= N_EDGES) return;
    int2 st = ((const int2*)ei)[e];  // x = src, y = tgt
    int slot = atomicAdd(&cnt[st.y], 1);
    if (slot < DMAX) {
        int idx = (st.y << 5) + slot;
        adjsrc[idx] = st.x;
        const float4* e4 = (const float4*)(E + (size_t)e * 8);
        float4 a = e4[0], b = e4[1];
        uint4 p;
        p.x = f2bf(a.x) | (f2bf(a.y) << 16);
        p.y = f2bf(a.z) | (f2bf(a.w) << 16);
        p.z = f2bf(b.x) | (f2bf(b.y) << 16);
        p.w = f2bf(b.z) | (f2bf(b.w) << 16);
        adjEb[idx] = p;
    }
}

// G gather: ONE WAVE PER NODE, lane = (es = lane>>3 edge slot, q = lane&7
// channel quad). One round = 8 edges with THREE memory instructions:
//   adjsrc (dword, 8 distinct addrs), adjEb (uint4), X row quad (float4 —
//   64 lanes fetch 8 full 128B rows in one instruction).
// Accumulate g[9] float4/lane; reduce across es via 3-level shfl_xor; lanes
// es==0 store G rows as coalesced float4.
//   G[n][d*32+i] = sum e_d * X[src][i] (d<8);  G[n][256+i] = sum X[src][i]
__global__ __launch_bounds__(256) void edge_gather(const float* __restrict__ X,
                                                   const int* __restrict__ cnt,
                                                   const int* __restrict__ adjsrc,
                                                   const uint4* __restrict__ adjEb,
                                                   float* __restrict__ G) {
    int t = blockIdx.x * blockDim.x + threadIdx.x;
    int n = t >> 6;
    if (n >= N_NODES) return;
    int lane = t & 63;
    int es = lane >> 3;   // edge slot within round (0..7)
    int q  = lane & 7;    // float4 quad of channels (0..7)

    int deg = min(cnt[n], DMAX);
    int base = n << 5;
    float4 z = make_float4(0.f, 0.f, 0.f, 0.f);
    float4 g0 = z, g1 = z, g2 = z, g3 = z, g4 = z, g5 = z, g6 = z, g7 = z, g8 = z;

    if (deg > 0) {
        int dlast = deg - 1;
        const float4* X4 = (const float4*)X;
        for (int c = 0; c < deg; c += 8) {
            int k = c + es;
            int kc = min(k, dlast);
            int s = adjsrc[base + kc];                 // 1 VMEM (8 addrs/wave)
            uint4 p = adjEb[base + kc];                // 1 VMEM
            float4 xv = X4[s * 8 + q];                 // 1 VMEM (8 rows/wave)
            if (k > dlast) xv = z;                     // pad contributes 0
            float e0 = bf2f(p.x & 0xffffu), e1 = bf2f(p.x >> 16);
            float e2 = bf2f(p.y & 0xffffu), e3 = bf2f(p.y >> 16);
            float e4 = bf2f(p.z & 0xffffu), e5 = bf2f(p.z >> 16);
            float e6 = bf2f(p.w & 0xffffu), e7 = bf2f(p.w >> 16);
            g0 = f4fma(e0, xv, g0); g1 = f4fma(e1, xv, g1);
            g2 = f4fma(e2, xv, g2); g3 = f4fma(e3, xv, g3);
            g4 = f4fma(e4, xv, g4); g5 = f4fma(e5, xv, g5);
            g6 = f4fma(e6, xv, g6); g7 = f4fma(e7, xv, g7);
            g8.x += xv.x; g8.y += xv.y; g8.z += xv.z; g8.w += xv.w;
        }
    }

    // reduce across edge-slot groups (lane bits 3,4,5)
#define RED4(v, m)                                                             \
    (v).x += __shfl_xor((v).x, m); (v).y += __shfl_xor((v).y, m);              \
    (v).z += __shfl_xor((v).z, m); (v).w += __shfl_xor((v).w, m);
#pragma unroll
    for (int m = 8; m <= 32; m <<= 1) {
        RED4(g0, m); RED4(g1, m); RED4(g2, m); RED4(g3, m);
        RED4(g4, m); RED4(g5, m); RED4(g6, m); RED4(g7, m); RED4(g8, m);
    }
#undef RED4

    if (es == 0) {
        float4* gr = (float4*)(G + (size_t)n * 288);   // 72 float4 per row
        gr[0 * 8 + q] = g0; gr[1 * 8 + q] = g1;
        gr[2 * 8 + q] = g2; gr[3 * 8 + q] = g3;
        gr[4 * 8 + q] = g4; gr[5 * 8 + q] = g5;
        gr[6 * 8 + q] = g6; gr[7 * 8 + q] = g7;
        gr[64 + q] = g8;
    }
}

// Epilogue GEMM (R17-validated): out[n][o] = sum_k Gext[n][k]*W'[k][o], K=320.
//   W' = [knw | knb | root] verbatim; Gext rows 0..287 = G, rows 288..319 = X.
// MB=32 nodes/block, 256 threads; thread (mg, jg) -> node nb+mg, outs 4jg..+3.
// W' staged in LDS (40KB); G/X in 9 transposed k-chunks (stride 33),
// grid-stride staging loops (288 > 256).
__global__ __launch_bounds__(256) void epi_gemm(const float4* __restrict__ G4,
                                                const float4* __restrict__ X4,
                                                const float4* __restrict__ knw4,
                                                const float4* __restrict__ knb4,
                                                const float4* __restrict__ root4,
                                                const float* __restrict__ bias,
                                                const float* __restrict__ dw,
                                                const float* __restrict__ db,
                                                float* __restrict__ H,
                                                float* __restrict__ util,
                                                int mode) {
    __shared__ float Ws[320 * 32];   // 40960 B
    __shared__ float Gs[36 * 33];    //  4752 B
    int t = threadIdx.x;
    int nb = blockIdx.x * MB;

    // stage W' = [knw | knb | root] verbatim
    {
        float4* d = (float4*)Ws;
#pragma unroll
        for (int c = 0; c < 10; ++c) {
            int idx = c * 256 + t;
            float4 v;
            if (idx < 2048) v = knw4[idx];
            else if (idx < 2304) v = knb4[idx - 2048];
            else v = root4[idx - 2304];
            d[idx] = v;
        }
    }

    int mg = t >> 3, jg = t & 7;
    float4 a0 = make_float4(0.f, 0.f, 0.f, 0.f);
    int n0 = nb + mg;

    for (int ch = 0; ch < 9; ++ch) {
        __syncthreads();  // Ws ready (ch 0) / previous chunk consumed
        if (ch < 8) {
            for (int idx = t; idx < MB * 9; idx += 256) {
                int n = idx / 9, k4 = idx % 9;
                float4 v = make_float4(0.f, 0.f, 0.f, 0.f);
                if (nb + n < N_NODES) v = G4[(size_t)(nb + n) * 72 + ch * 9 + k4];
                int r = k4 * 4;
                Gs[(r + 0) * 33 + n] = v.x; Gs[(r + 1) * 33 + n] = v.y;
                Gs[(r + 2) * 33 + n] = v.z; Gs[(r + 3) * 33 + n] = v.w;
            }
        } else {
            for (int idx = t; idx < MB * 8; idx += 256) {
                int n = idx / 8, k4 = idx % 8;
                float4 v = make_float4(0.f, 0.f, 0.f, 0.f);
                if (nb + n < N_NODES) v = X4[(size_t)(nb + n) * 8 + k4];
                int r = k4 * 4;
                Gs[(r + 0) * 33 + n] = v.x; Gs[(r + 1) * 33 + n] = v.y;
                Gs[(r + 2) * 33 + n] = v.z; Gs[(r + 3) * 33 + n] = v.w;
            }
        }
        __syncthreads();
        int kbase = (ch < 8) ? ch * 36 : 288;
        int klen = (ch < 8) ? 36 : 32;
        for (int kk = 0; kk < klen; ++kk) {
            float4 w = *(const float4*)&Ws[(kbase + kk) * 32 + jg * 4];
            float g = Gs[kk * 33 + mg];
            a0 = f4fma(g, w, a0);
        }
    }

    float4 b = ((const float4*)bias)[jg];
    if (mode == 0) {
        if (n0 < N_NODES) {
            float4 v;
            v.x = fmaxf(a0.x + b.x, 0.f); v.y = fmaxf(a0.y + b.y, 0.f);
            v.z = fmaxf(a0.z + b.z, 0.f); v.w = fmaxf(a0.w + b.w, 0.f);
            ((float4*)H)[n0 * 8 + jg] = v;
        }
    } else {
        float4 dv = ((const float4*)dw)[jg];
        float p0 = fmaxf(a0.x + b.x, 0.f) * dv.x + fmaxf(a0.y + b.y, 0.f) * dv.y
                 + fmaxf(a0.z + b.z, 0.f) * dv.z + fmaxf(a0.w + b.w, 0.f) * dv.w;
        p0 += __shfl_xor(p0, 1);
        p0 += __shfl_xor(p0, 2);
        p0 += __shfl_xor(p0, 4);
        if (jg == 0 && n0 < N_NODES) util[n0] = p0 + db[0];
    }
}

// out[p] = util[idx_b[p]] - util[idx_a[p]]
__global__ void pair_kernel(const float* __restrict__ util, const int* __restrict__ ia,
                            const int* __restrict__ ib, float* __restrict__ out) {
    int p = blockIdx.x * blockDim.x + threadIdx.x;
    if (p >= N_PAIRS) return;
    out[p] = util[ib[p]] - util[ia[p]];
}

extern "C" void kernel_launch(void* const* d_in, const int* in_sizes, int n_in,
                              void* d_out, int out_size, void* d_ws, size_t ws_size,
                              hipStream_t stream) {
    const float* x     = (const float*)d_in[0];
    const float* e     = (const float*)d_in[1];
    const float* knw1  = (const float*)d_in[2];
    const float* knb1  = (const float*)d_in[3];
    const float* root1 = (const float*)d_in[4];
    const float* bias1 = (const float*)d_in[5];
    const float* knw2  = (const float*)d_in[6];
    const float* knb2  = (const float*)d_in[7];
    const float* root2 = (const float*)d_in[8];
    const float* bias2 = (const float*)d_in[9];
    const float* dw    = (const float*)d_in[10];
    const float* db    = (const float*)d_in[11];
    const int*   ei    = (const int*)d_in[12];
    const int*   ia    = (const int*)d_in[13];
    const int*   ib    = (const int*)d_in[14];
    float* out = (float*)d_out;

    float* ws = (float*)d_ws;
    float* G      = ws;                       // 20000*288 = 5,760,000 floats
    float* H      = ws + 5760000;             // 640,000
    float* util   = ws + 6400000;             // 20,000
    int*   cnt    = (int*)(ws + 6420000);     // 20,000
    int*   adjsrc = (int*)(ws + 6440000);     // 640,000 ints
    uint4* adjEb  = (uint4*)(ws + 7080000);   // 640,000 uint4 (16B-aligned)

    int nblk_epi = (N_NODES + MB - 1) / MB;          // 625
    int nblk_gat = (N_NODES * 64) / 256;             // 5000

    // ---- adjacency ----
    zero_cnt<<<(N_NODES + 255) / 256, 256, 0, stream>>>(cnt);
    fill_adj<<<(N_EDGES + 255) / 256, 256, 0, stream>>>(ei, e, cnt, adjsrc, adjEb);

    // ---- layer 1 ----
    edge_gather<<<nblk_gat, 256, 0, stream>>>(x, cnt, adjsrc, adjEb, G);
    epi_gemm<<<nblk_epi, 256, 0, stream>>>((const float4*)G, (const float4*)x,
                                           (const float4*)knw1, (const float4*)knb1,
                                           (const float4*)root1, bias1, dw, db,
                                           H, util, 0);
    // ---- layer 2 (+ readout) ----
    edge_gather<<<nblk_gat, 256, 0, stream>>>(H, cnt, adjsrc, adjEb, G);
    epi_gemm<<<nblk_epi, 256, 0, stream>>>((const float4*)G, (const float4*)H,
                                           (const float4*)knw2, (const float4*)knb2,
                                           (const float4*)root2, bias2, dw, db,
                                           H, util, 1);

    // ---- pairs ----
    pair_kernel<<<(N_PAIRS + 255) / 256, 256, 0, stream>>>(util, ia, ib, out);
}

// Round 23
// 118.159 us; speedup vs baseline: 1.0351x; 1.0351x over previous
//
#include <hip/hip_runtime.h>

#define N_NODES 20000
#define N_EDGES 160000
#define N_PAIRS 50000
#define DMAX 32
#define MB 32          // nodes per epi block (625 blocks -> 2.4 blocks/CU)
// F_IN = CHANNELS = 32, EDGE_DIM = 8; G row = 288 floats (knw 256 + knb 32)
// R22 = R18-exact pipeline + gather1 launched 3x (timing probe, idempotent).

__device__ __forceinline__ float4 f4fma(float s, float4 w, float4 a) {
    a.x += s * w.x; a.y += s * w.y; a.z += s * w.z; a.w += s * w.w;
    return a;
}

__device__ __forceinline__ float bf2f(unsigned int u) {  // low 16 bits = bf16
    return __uint_as_float(u << 16);
}
__device__ __forceinline__ unsigned int f2bf(float f) {  // RNE, low 16 bits
    unsigned int u = __float_as_uint(f);
    u += 0x7fffu + ((u >> 16) & 1u);
    return u >> 16;
}

__global__ void zero_cnt(int* __restrict__ c) {
    int t = blockIdx.x * blockDim.x + threadIdx.x;
    if (t < N_NODES) c[t] = 0;
}

// adjacency by target: slot -> src (int) + bf16-packed E row (uint4, 16B).
__global__ __launch_bounds__(256) void fill_adj(const int* __restrict__ ei,
                                                const float* __restrict__ E,
                                                int* __restrict__ cnt,
                                                int* __restrict__ adjsrc,
                                                uint4* __restrict__ adjEb) {
    int e = blockIdx.x * blockDim.x + threadIdx.x;
    if (e >= N_EDGES) return;
    int2 st = ((const int2*)ei)[e];  // x = src, y = tgt
    int slot = atomicAdd(&cnt[st.y], 1);
    if (slot < DMAX) {
        int idx = (st.y << 5) + slot;
        adjsrc[idx] = st.x;
        const float4* e4 = (const float4*)(E + (size_t)e * 8);
        float4 a = e4[0], b = e4[1];
        uint4 p;
        p.x = f2bf(a.x) | (f2bf(a.y) << 16);
        p.y = f2bf(a.z) | (f2bf(a.w) << 16);
        p.z = f2bf(b.x) | (f2bf(b.y) << 16);
        p.w = f2bf(b.z) | (f2bf(b.w) << 16);
        adjEb[idx] = p;
    }
}

#define EDGE_FMA_P(p, xv)                                                      \
    g0 += bf2f((p).x & 0xffffu) * (xv); g1 += bf2f((p).x >> 16) * (xv);        \
    g2 += bf2f((p).y & 0xffffu) * (xv); g3 += bf2f((p).y >> 16) * (xv);        \
    g4 += bf2f((p).z & 0xffffu) * (xv); g5 += bf2f((p).z >> 16) * (xv);        \
    g6 += bf2f((p).w & 0xffffu) * (xv); g7 += bf2f((p).w >> 16) * (xv);        \
    g8 += (xv);

// G gather (R14/R18-validated): ONE WAVE PER NODE; chunks of 8 edges (4 per
// half), independent slot/E/X loads issued before FMAs.
__global__ __launch_bounds__(256) void edge_gather(const float* __restrict__ X,
                                                   const int* __restrict__ cnt,
                                                   const int* __restrict__ adjsrc,
                                                   const uint4* __restrict__ adjEb,
                                                   float* __restrict__ G) {
    int t = blockIdx.x * blockDim.x + threadIdx.x;
    int n = t >> 6;
    if (n >= N_NODES) return;
    int lane = t & 63;
    int i = lane & 31;
    int half = lane >> 5;

    int deg = min(cnt[n], DMAX);
    int base = n << 5;
    float g0 = 0.f, g1 = 0.f, g2 = 0.f, g3 = 0.f;
    float g4 = 0.f, g5 = 0.f, g6 = 0.f, g7 = 0.f, g8 = 0.f;

    int c = 0;
    for (; c + 8 <= deg; c += 8) {
        int k0 = base + c + half * 4;
        int s0 = adjsrc[k0 + 0];
        int s1 = adjsrc[k0 + 1];
        int s2 = adjsrc[k0 + 2];
        int s3 = adjsrc[k0 + 3];
        uint4 p0 = adjEb[k0 + 0];
        uint4 p1 = adjEb[k0 + 1];
        uint4 p2 = adjEb[k0 + 2];
        uint4 p3 = adjEb[k0 + 3];
        float xv0 = X[s0 * 32 + i];
        float xv1 = X[s1 * 32 + i];
        float xv2 = X[s2 * 32 + i];
        float xv3 = X[s3 * 32 + i];
        EDGE_FMA_P(p0, xv0);
        EDGE_FMA_P(p1, xv1);
        EDGE_FMA_P(p2, xv2);
        EDGE_FMA_P(p3, xv3);
    }
    for (int k = c + half; k < deg; k += 2) {
        int s = adjsrc[base + k];
        uint4 p = adjEb[base + k];
        float xv = X[s * 32 + i];
        EDGE_FMA_P(p, xv);
    }

    g0 += __shfl_xor(g0, 32); g1 += __shfl_xor(g1, 32);
    g2 += __shfl_xor(g2, 32); g3 += __shfl_xor(g3, 32);
    g4 += __shfl_xor(g4, 32); g5 += __shfl_xor(g5, 32);
    g6 += __shfl_xor(g6, 32); g7 += __shfl_xor(g7, 32);
    g8 += __shfl_xor(g8, 32);

    if (half == 0) {
        float* gr = G + (size_t)n * 288;
        gr[0 * 32 + i] = g0; gr[1 * 32 + i] = g1;
        gr[2 * 32 + i] = g2; gr[3 * 32 + i] = g3;
        gr[4 * 32 + i] = g4; gr[5 * 32 + i] = g5;
        gr[6 * 32 + i] = g6; gr[7 * 32 + i] = g7;
        gr[256 + i] = g8;
    }
}

// Epilogue GEMM (R17-validated).
__global__ __launch_bounds__(256) void epi_gemm(const float4* __restrict__ G4,
                                                const float4* __restrict__ X4,
                                                const float4* __restrict__ knw4,
                                                const float4* __restrict__ knb4,
                                                const float4* __restrict__ root4,
                                                const float* __restrict__ bias,
                                                const float* __restrict__ dw,
                                                const float* __restrict__ db,
                                                float* __restrict__ H,
                                                float* __restrict__ util,
                                                int mode) {
    __shared__ float Ws[320 * 32];   // 40960 B
    __shared__ float Gs[36 * 33];    //  4752 B
    int t = threadIdx.x;
    int nb = blockIdx.x * MB;

    {
        float4* d = (float4*)Ws;
#pragma unroll
        for (int c = 0; c < 10; ++c) {
            int idx = c * 256 + t;
            float4 v;
            if (idx < 2048) v = knw4[idx];
            else if (idx < 2304) v = knb4[idx - 2048];
            else v = root4[idx - 2304];
            d[idx] = v;
        }
    }

    int mg = t >> 3, jg = t & 7;
    float4 a0 = make_float4(0.f, 0.f, 0.f, 0.f);
    int n0 = nb + mg;

    for (int ch = 0; ch < 9; ++ch) {
        __syncthreads();
        if (ch < 8) {
            for (int idx = t; idx < MB * 9; idx += 256) {
                int n = idx / 9, k4 = idx % 9;
                float4 v = make_float4(0.f, 0.f, 0.f, 0.f);
                if (nb + n < N_NODES) v = G4[(size_t)(nb + n) * 72 + ch * 9 + k4];
                int r = k4 * 4;
                Gs[(r + 0) * 33 + n] = v.x; Gs[(r + 1) * 33 + n] = v.y;
                Gs[(r + 2) * 33 + n] = v.z; Gs[(r + 3) * 33 + n] = v.w;
            }
        } else {
            for (int idx = t; idx < MB * 8; idx += 256) {
                int n = idx / 8, k4 = idx % 8;
                float4 v = make_float4(0.f, 0.f, 0.f, 0.f);
                if (nb + n < N_NODES) v = X4[(size_t)(nb + n) * 8 + k4];
                int r = k4 * 4;
                Gs[(r + 0) * 33 + n] = v.x; Gs[(r + 1) * 33 + n] = v.y;
                Gs[(r + 2) * 33 + n] = v.z; Gs[(r + 3) * 33 + n] = v.w;
            }
        }
        __syncthreads();
        int kbase = (ch < 8) ? ch * 36 : 288;
        int klen = (ch < 8) ? 36 : 32;
        for (int kk = 0; kk < klen; ++kk) {
            float4 w = *(const float4*)&Ws[(kbase + kk) * 32 + jg * 4];
            float g = Gs[kk * 33 + mg];
            a0 = f4fma(g, w, a0);
        }
    }

    float4 b = ((const float4*)bias)[jg];
    if (mode == 0) {
        if (n0 < N_NODES) {
            float4 v;
            v.x = fmaxf(a0.x + b.x, 0.f); v.y = fmaxf(a0.y + b.y, 0.f);
            v.z = fmaxf(a0.z + b.z, 0.f); v.w = fmaxf(a0.w + b.w, 0.f);
            ((float4*)H)[n0 * 8 + jg] = v;
        }
    } else {
        float4 dv = ((const float4*)dw)[jg];
        float p0 = fmaxf(a0.x + b.x, 0.f) * dv.x + fmaxf(a0.y + b.y, 0.f) * dv.y
                 + fmaxf(a0.z + b.z, 0.f) * dv.z + fmaxf(a0.w + b.w, 0.f) * dv.w;
        p0 += __shfl_xor(p0, 1);
        p0 += __shfl_xor(p0, 2);
        p0 += __shfl_xor(p0, 4);
        if (jg == 0 && n0 < N_NODES) util[n0] = p0 + db[0];
    }
}

// out[p] = util[idx_b[p]] - util[idx_a[p]]
__global__ void pair_kernel(const float* __restrict__ util, const int* __restrict__ ia,
                            const int* __restrict__ ib, float* __restrict__ out) {
    int p = blockIdx.x * blockDim.x + threadIdx.x;
    if (p >= N_PAIRS) return;
    out[p] = util[ib[p]] - util[ia[p]];
}

extern "C" void kernel_launch(void* const* d_in, const int* in_sizes, int n_in,
                              void* d_out, int out_size, void* d_ws, size_t ws_size,
                              hipStream_t stream) {
    const float* x     = (const float*)d_in[0];
    const float* e     = (const float*)d_in[1];
    const float* knw1  = (const float*)d_in[2];
    const float* knb1  = (const float*)d_in[3];
    const float* root1 = (const float*)d_in[4];
    const float* bias1 = (const float*)d_in[5];
    const float* knw2  = (const float*)d_in[6];
    const float* knb2  = (const float*)d_in[7];
    const float* root2 = (const float*)d_in[8];
    const float* bias2 = (const float*)d_in[9];
    const float* dw    = (const float*)d_in[10];
    const float* db    = (const float*)d_in[11];
    const int*   ei    = (const int*)d_in[12];
    const int*   ia    = (const int*)d_in[13];
    const int*   ib    = (const int*)d_in[14];
    float* out = (float*)d_out;

    float* ws = (float*)d_ws;
    float* G      = ws;                       // 20000*288 = 5,760,000 floats
    float* H      = ws + 5760000;             // 640,000
    float* util   = ws + 6400000;             // 20,000
    int*   cnt    = (int*)(ws + 6420000);     // 20,000
    int*   adjsrc = (int*)(ws + 6440000);     // 640,000 ints
    uint4* adjEb  = (uint4*)(ws + 7080000);   // 640,000 uint4 (16B-aligned)

    int nblk_epi = (N_NODES + MB - 1) / MB;          // 625
    int nblk_gat = (N_NODES * 64) / 256;             // 5000

    // ---- adjacency ----
    zero_cnt<<<(N_NODES + 255) / 256, 256, 0, stream>>>(cnt);
    fill_adj<<<(N_EDGES + 255) / 256, 256, 0, stream>>>(ei, e, cnt, adjsrc, adjEb);

    // ---- layer 1 (gather launched 3x: timing probe, idempotent) ----
    edge_gather<<<nblk_gat, 256, 0, stream>>>(x, cnt, adjsrc, adjEb, G);
    edge_gather<<<nblk_gat, 256, 0, stream>>>(x, cnt, adjsrc, adjEb, G);
    edge_gather<<<nblk_gat, 256, 0, stream>>>(x, cnt, adjsrc, adjEb, G);
    epi_gemm<<<nblk_epi, 256, 0, stream>>>((const float4*)G, (const float4*)x,
                                           (const float4*)knw1, (const float4*)knb1,
                                           (const float4*)root1, bias1, dw, db,
                                           H, util, 0);
    // ---- layer 2 (+ readout) ----
    edge_gather<<<nblk_gat, 256, 0, stream>>>(H, cnt, adjsrc, adjEb, G);
    epi_gemm<<<nblk_epi, 256, 0, stream>>>((const float4*)G, (const float4*)H,
                                           (const float4*)knw2, (const float4*)knb2,
                                           (const float4*)root2, bias2, dw, db,
                                           H, util, 1);

    // ---- pairs ----
    pair_kernel<<<(N_PAIRS + 255) / 256, 256, 0, stream>>>(util, ia, ib, out);
}

// Round 24
// 95.688 us; speedup vs baseline: 1.2782x; 1.2348x over previous
//
#include <hip/hip_runtime.h>

#define N_NODES 20000
#define N_EDGES 160000
#define N_PAIRS 50000
#define DMAX 32
// F_IN = CHANNELS = 32, EDGE_DIM = 8; G row = 288 floats (knw 256 + knb 32)

__device__ __forceinline__ float4 f4fma(float s, float4 w, float4 a) {
    a.x += s * w.x; a.y += s * w.y; a.z += s * w.z; a.w += s * w.w;
    return a;
}

__device__ __forceinline__ float bf2f(unsigned int u) {  // low 16 bits = bf16
    return __uint_as_float(u << 16);
}
__device__ __forceinline__ unsigned int f2bf(float f) {  // RNE, low 16 bits
    unsigned int u = __float_as_uint(f);
    u += 0x7fffu + ((u >> 16) & 1u);
    return u >> 16;
}

__global__ void zero_cnt(int* __restrict__ c) {
    int t = blockIdx.x * blockDim.x + threadIdx.x;
    if (t < N_NODES) c[t] = 0;
}

// adjacency by target: slot -> src (int) + bf16-packed E row (uint4, 16B).
__global__ __launch_bounds__(256) void fill_adj(const int* __restrict__ ei,
                                                const float* __restrict__ E,
                                                int* __restrict__ cnt,
                                                int* __restrict__ adjsrc,
                                                uint4* __restrict__ adjEb) {
    int e = blockIdx.x * blockDim.x + threadIdx.x;
    if (e >= N_EDGES) return;
    int2 st = ((const int2*)ei)[e];  // x = src, y = tgt
    int slot = atomicAdd(&cnt[st.y], 1);
    if (slot < DMAX) {
        int idx = (st.y << 5) + slot;
        adjsrc[idx] = st.x;
        const float4* e4 = (const float4*)(E + (size_t)e * 8);
        float4 a = e4[0], b = e4[1];
        uint4 p;
        p.x = f2bf(a.x) | (f2bf(a.y) << 16);
        p.y = f2bf(a.z) | (f2bf(a.w) << 16);
        p.z = f2bf(b.x) | (f2bf(b.y) << 16);
        p.w = f2bf(b.z) | (f2bf(b.w) << 16);
        adjEb[idx] = p;
    }
}

#define EDGE_FMA_P(p, xv)                                                      \
    g0 += bf2f((p).x & 0xffffu) * (xv); g1 += bf2f((p).x >> 16) * (xv);        \
    g2 += bf2f((p).y & 0xffffu) * (xv); g3 += bf2f((p).y >> 16) * (xv);        \
    g4 += bf2f((p).z & 0xffffu) * (xv); g5 += bf2f((p).z >> 16) * (xv);        \
    g6 += bf2f((p).w & 0xffffu) * (xv); g7 += bf2f((p).w >> 16) * (xv);        \
    g8 += (xv);

// G gather (R14/R18-validated): ONE WAVE PER NODE; chunks of 8 edges (4 per
// half), independent slot/E/X loads issued before FMAs.
__global__ __launch_bounds__(256) void edge_gather(const float* __restrict__ X,
                                                   const int* __restrict__ cnt,
                                                   const int* __restrict__ adjsrc,
                                                   const uint4* __restrict__ adjEb,
                                                   float* __restrict__ G) {
    int t = blockIdx.x * blockDim.x + threadIdx.x;
    int n = t >> 6;
    if (n >= N_NODES) return;
    int lane = t & 63;
    int i = lane & 31;
    int half = lane >> 5;

    int deg = min(cnt[n], DMAX);
    int base = n << 5;
    float g0 = 0.f, g1 = 0.f, g2 = 0.f, g3 = 0.f;
    float g4 = 0.f, g5 = 0.f, g6 = 0.f, g7 = 0.f, g8 = 0.f;

    int c = 0;
    for (; c + 8 <= deg; c += 8) {
        int k0 = base + c + half * 4;
        int s0 = adjsrc[k0 + 0];
        int s1 = adjsrc[k0 + 1];
        int s2 = adjsrc[k0 + 2];
        int s3 = adjsrc[k0 + 3];
        uint4 p0 = adjEb[k0 + 0];
        uint4 p1 = adjEb[k0 + 1];
        uint4 p2 = adjEb[k0 + 2];
        uint4 p3 = adjEb[k0 + 3];
        float xv0 = X[s0 * 32 + i];
        float xv1 = X[s1 * 32 + i];
        float xv2 = X[s2 * 32 + i];
        float xv3 = X[s3 * 32 + i];
        EDGE_FMA_P(p0, xv0);
        EDGE_FMA_P(p1, xv1);
        EDGE_FMA_P(p2, xv2);
        EDGE_FMA_P(p3, xv3);
    }
    for (int k = c + half; k < deg; k += 2) {
        int s = adjsrc[base + k];
        uint4 p = adjEb[base + k];
        float xv = X[s * 32 + i];
        EDGE_FMA_P(p, xv);
    }

    g0 += __shfl_xor(g0, 32); g1 += __shfl_xor(g1, 32);
    g2 += __shfl_xor(g2, 32); g3 += __shfl_xor(g3, 32);
    g4 += __shfl_xor(g4, 32); g5 += __shfl_xor(g5, 32);
    g6 += __shfl_xor(g6, 32); g7 += __shfl_xor(g7, 32);
    g8 += __shfl_xor(g8, 32);

    if (half == 0) {
        float* gr = G + (size_t)n * 288;
        gr[0 * 32 + i] = g0; gr[1 * 32 + i] = g1;
        gr[2 * 32 + i] = g2; gr[3 * 32 + i] = g3;
        gr[4 * 32 + i] = g4; gr[5 * 32 + i] = g5;
        gr[6 * 32 + i] = g6; gr[7 * 32 + i] = g7;
        gr[256 + i] = g8;
    }
}

// Epilogue GEMM, register-tiled Mr=4 (R23): out[n][o] = sum_k Gext[n][k]*W'[k][o].
//   W' = [knw|knb|root] verbatim in LDS (40KB); G read DIRECTLY from global
//   (no LDS round-trip): per k4, 4 Ws ds_read_b128 shared across 4 nodes.
// 128 threads/block = 16 mg x 8 jg; thread -> nodes n0..n0+3, outs 4jg..4jg+3.
// 313 blocks x 64 nodes. Total waves 626 (was 2500) -> LDS-port time /4.
// mode 0: H[n][o] = relu(out + bias[o]);  mode 1: util[n] = db + relu(.)@dw
__global__ __launch_bounds__(128) void epi_gemm(const float4* __restrict__ G4,
                                                const float4* __restrict__ X4,
                                                const float4* __restrict__ knw4,
                                                const float4* __restrict__ knb4,
                                                const float4* __restrict__ root4,
                                                const float* __restrict__ bias,
                                                const float* __restrict__ dw,
                                                const float* __restrict__ db,
                                                float* __restrict__ H,
                                                float* __restrict__ util,
                                                int mode) {
    __shared__ float Ws[320 * 32];   // 40960 B
    int t = threadIdx.x;

    // stage W' = [knw | knb | root] verbatim (2560 float4 / 128 thr = 20 each)
    {
        float4* d = (float4*)Ws;
#pragma unroll
        for (int c = 0; c < 20; ++c) {
            int idx = c * 128 + t;
            float4 v;
            if (idx < 2048) v = knw4[idx];
            else if (idx < 2304) v = knb4[idx - 2048];
            else v = root4[idx - 2304];
            d[idx] = v;
        }
    }
    __syncthreads();

    int mg = t >> 3, jg = t & 7;
    int n0 = blockIdx.x * 64 + mg * 4;
    int nm0 = min(n0 + 0, N_NODES - 1);
    int nm1 = min(n0 + 1, N_NODES - 1);
    int nm2 = min(n0 + 2, N_NODES - 1);
    int nm3 = min(n0 + 3, N_NODES - 1);

    float4 z = make_float4(0.f, 0.f, 0.f, 0.f);
    float4 a0 = z, a1 = z, a2 = z, a3 = z;

#pragma unroll 2
    for (int k4 = 0; k4 < 72; ++k4) {
        float4 g0 = G4[(size_t)nm0 * 72 + k4];
        float4 g1 = G4[(size_t)nm1 * 72 + k4];
        float4 g2 = G4[(size_t)nm2 * 72 + k4];
        float4 g3 = G4[(size_t)nm3 * 72 + k4];
        const float* wb = &Ws[(k4 * 4) * 32 + jg * 4];
        float4 w0 = *(const float4*)(wb);
        float4 w1 = *(const float4*)(wb + 32);
        float4 w2 = *(const float4*)(wb + 64);
        float4 w3 = *(const float4*)(wb + 96);
        a0 = f4fma(g0.x, w0, a0); a0 = f4fma(g0.y, w1, a0);
        a0 = f4fma(g0.z, w2, a0); a0 = f4fma(g0.w, w3, a0);
        a1 = f4fma(g1.x, w0, a1); a1 = f4fma(g1.y, w1, a1);
        a1 = f4fma(g1.z, w2, a1); a1 = f4fma(g1.w, w3, a1);
        a2 = f4fma(g2.x, w0, a2); a2 = f4fma(g2.y, w1, a2);
        a2 = f4fma(g2.z, w2, a2); a2 = f4fma(g2.w, w3, a2);
        a3 = f4fma(g3.x, w0, a3); a3 = f4fma(g3.y, w1, a3);
        a3 = f4fma(g3.z, w2, a3); a3 = f4fma(g3.w, w3, a3);
    }
    // root term: k = 288..319 sourced from X rows
#pragma unroll 2
    for (int k4 = 0; k4 < 8; ++k4) {
        float4 g0 = X4[(size_t)nm0 * 8 + k4];
        float4 g1 = X4[(size_t)nm1 * 8 + k4];
        float4 g2 = X4[(size_t)nm2 * 8 + k4];
        float4 g3 = X4[(size_t)nm3 * 8 + k4];
        const float* wb = &Ws[(288 + k4 * 4) * 32 + jg * 4];
        float4 w0 = *(const float4*)(wb);
        float4 w1 = *(const float4*)(wb + 32);
        float4 w2 = *(const float4*)(wb + 64);
        float4 w3 = *(const float4*)(wb + 96);
        a0 = f4fma(g0.x, w0, a0); a0 = f4fma(g0.y, w1, a0);
        a0 = f4fma(g0.z, w2, a0); a0 = f4fma(g0.w, w3, a0);
        a1 = f4fma(g1.x, w0, a1); a1 = f4fma(g1.y, w1, a1);
        a1 = f4fma(g1.z, w2, a1); a1 = f4fma(g1.w, w3, a1);
        a2 = f4fma(g2.x, w0, a2); a2 = f4fma(g2.y, w1, a2);
        a2 = f4fma(g2.z, w2, a2); a2 = f4fma(g2.w, w3, a2);
        a3 = f4fma(g3.x, w0, a3); a3 = f4fma(g3.y, w1, a3);
        a3 = f4fma(g3.z, w2, a3); a3 = f4fma(g3.w, w3, a3);
    }

    float4 b = ((const float4*)bias)[jg];
    if (mode == 0) {
        float4* H4 = (float4*)H;
#define STORE_H(am, m)                                                         \
        if (n0 + m < N_NODES) {                                                \
            float4 v;                                                          \
            v.x = fmaxf((am).x + b.x, 0.f); v.y = fmaxf((am).y + b.y, 0.f);    \
            v.z = fmaxf((am).z + b.z, 0.f); v.w = fmaxf((am).w + b.w, 0.f);    \
            H4[(n0 + m) * 8 + jg] = v;                                         \
        }
        STORE_H(a0, 0); STORE_H(a1, 1); STORE_H(a2, 2); STORE_H(a3, 3);
#undef STORE_H
    } else {
        float4 dv = ((const float4*)dw)[jg];
#define UTIL_P(am) (fmaxf((am).x + b.x, 0.f) * dv.x                            \
                  + fmaxf((am).y + b.y, 0.f) * dv.y                            \
                  + fmaxf((am).z + b.z, 0.f) * dv.z                            \
                  + fmaxf((am).w + b.w, 0.f) * dv.w)
        float p0 = UTIL_P(a0), p1 = UTIL_P(a1), p2 = UTIL_P(a2), p3 = UTIL_P(a3);
#undef UTIL_P
        p0 += __shfl_xor(p0, 1); p1 += __shfl_xor(p1, 1);
        p2 += __shfl_xor(p2, 1); p3 += __shfl_xor(p3, 1);
        p0 += __shfl_xor(p0, 2); p1 += __shfl_xor(p1, 2);
        p2 += __shfl_xor(p2, 2); p3 += __shfl_xor(p3, 2);
        p0 += __shfl_xor(p0, 4); p1 += __shfl_xor(p1, 4);
        p2 += __shfl_xor(p2, 4); p3 += __shfl_xor(p3, 4);
        if (jg == 0) {
            float dbv = db[0];
            if (n0 + 0 < N_NODES) util[n0 + 0] = p0 + dbv;
            if (n0 + 1 < N_NODES) util[n0 + 1] = p1 + dbv;
            if (n0 + 2 < N_NODES) util[n0 + 2] = p2 + dbv;
            if (n0 + 3 < N_NODES) util[n0 + 3] = p3 + dbv;
        }
    }
}

// out[p] = util[idx_b[p]] - util[idx_a[p]]
__global__ void pair_kernel(const float* __restrict__ util, const int* __restrict__ ia,
                            const int* __restrict__ ib, float* __restrict__ out) {
    int p = blockIdx.x * blockDim.x + threadIdx.x;
    if (p >= N_PAIRS) return;
    out[p] = util[ib[p]] - util[ia[p]];
}

extern "C" void kernel_launch(void* const* d_in, const int* in_sizes, int n_in,
                              void* d_out, int out_size, void* d_ws, size_t ws_size,
                              hipStream_t stream) {
    const float* x     = (const float*)d_in[0];
    const float* e     = (const float*)d_in[1];
    const float* knw1  = (const float*)d_in[2];
    const float* knb1  = (const float*)d_in[3];
    const float* root1 = (const float*)d_in[4];
    const float* bias1 = (const float*)d_in[5];
    const float* knw2  = (const float*)d_in[6];
    const float* knb2  = (const float*)d_in[7];
    const float* root2 = (const float*)d_in[8];
    const float* bias2 = (const float*)d_in[9];
    const float* dw    = (const float*)d_in[10];
    const float* db    = (const float*)d_in[11];
    const int*   ei    = (const int*)d_in[12];
    const int*   ia    = (const int*)d_in[13];
    const int*   ib    = (const int*)d_in[14];
    float* out = (float*)d_out;

    float* ws = (float*)d_ws;
    float* G      = ws;                       // 20000*288 = 5,760,000 floats
    float* H      = ws + 5760000;             // 640,000
    float* util   = ws + 6400000;             // 20,000
    int*   cnt    = (int*)(ws + 6420000);     // 20,000
    int*   adjsrc = (int*)(ws + 6440000);     // 640,000 ints
    uint4* adjEb  = (uint4*)(ws + 7080000);   // 640,000 uint4 (16B-aligned)

    int nblk_epi = (N_NODES + 63) / 64;              // 313
    int nblk_gat = (N_NODES * 64) / 256;             // 5000

    // ---- adjacency ----
    zero_cnt<<<(N_NODES + 255) / 256, 256, 0, stream>>>(cnt);
    fill_adj<<<(N_EDGES + 255) / 256, 256, 0, stream>>>(ei, e, cnt, adjsrc, adjEb);

    // ---- layer 1 ----
    edge_gather<<<nblk_gat, 256, 0, stream>>>(x, cnt, adjsrc, adjEb, G);
    epi_gemm<<<nblk_epi, 128, 0, stream>>>((const float4*)G, (const float4*)x,
                                           (const float4*)knw1, (const float4*)knb1,
                                           (const float4*)root1, bias1, dw, db,
                                           H, util, 0);
    // ---- layer 2 (+ readout) ----
    edge_gather<<<nblk_gat, 256, 0, stream>>>(H, cnt, adjsrc, adjEb, G);
    epi_gemm<<<nblk_epi, 128, 0, stream>>>((const float4*)G, (const float4*)H,
                                           (const float4*)knw2, (const float4*)knb2,
                                           (const float4*)root2, bias2, dw, db,
                                           H, util, 1);

    // ---- pairs ----
    pair_kernel<<<(N_PAIRS + 255) / 256, 256, 0, stream>>>(util, ia, ib, out);
}

// Round 25
// 83.157 us; speedup vs baseline: 1.4708x; 1.1507x over previous
//
#include <hip/hip_runtime.h>

#define N_NODES 20000
#define N_EDGES 160000
#define N_PAIRS 50000
#define DMAX 32
// F_IN = CHANNELS = 32, EDGE_DIM = 8; G row = 288 floats (knw 256 + knb 32)

__device__ __forceinline__ float4 f4fma(float s, float4 w, float4 a) {
    a.x += s * w.x; a.y += s * w.y; a.z += s * w.z; a.w += s * w.w;
    return a;
}

__device__ __forceinline__ float bf2f(unsigned int u) {  // low 16 bits = bf16
    return __uint_as_float(u << 16);
}
__device__ __forceinline__ unsigned int f2bf(float f) {  // RNE, low 16 bits
    unsigned int u = __float_as_uint(f);
    u += 0x7fffu + ((u >> 16) & 1u);
    return u >> 16;
}

__global__ void zero_cnt(int* __restrict__ c) {
    int t = blockIdx.x * blockDim.x + threadIdx.x;
    if (t < N_NODES) c[t] = 0;
}

// adjacency by target: slot -> src (int) + bf16-packed E row (uint4, 16B).
__global__ __launch_bounds__(256) void fill_adj(const int* __restrict__ ei,
                                                const float* __restrict__ E,
                                                int* __restrict__ cnt,
                                                int* __restrict__ adjsrc,
                                                uint4* __restrict__ adjEb) {
    int e = blockIdx.x * blockDim.x + threadIdx.x;
    if (e >= N_EDGES) return;
    int2 st = ((const int2*)ei)[e];  // x = src, y = tgt
    int slot = atomicAdd(&cnt[st.y], 1);
    if (slot < DMAX) {
        int idx = (st.y << 5) + slot;
        adjsrc[idx] = st.x;
        const float4* e4 = (const float4*)(E + (size_t)e * 8);
        float4 a = e4[0], b = e4[1];
        uint4 p;
        p.x = f2bf(a.x) | (f2bf(a.y) << 16);
        p.y = f2bf(a.z) | (f2bf(a.w) << 16);
        p.z = f2bf(b.x) | (f2bf(b.y) << 16);
        p.w = f2bf(b.z) | (f2bf(b.w) << 16);
        adjEb[idx] = p;
    }
}

#define EDGE_FMA_P(p, xv)                                                      \
    g0 += bf2f((p).x & 0xffffu) * (xv); g1 += bf2f((p).x >> 16) * (xv);        \
    g2 += bf2f((p).y & 0xffffu) * (xv); g3 += bf2f((p).y >> 16) * (xv);        \
    g4 += bf2f((p).z & 0xffffu) * (xv); g5 += bf2f((p).z >> 16) * (xv);        \
    g6 += bf2f((p).w & 0xffffu) * (xv); g7 += bf2f((p).w >> 16) * (xv);        \
    g8 += (xv);

// G gather (R14/R18-validated): ONE WAVE PER NODE; chunks of 8 edges (4 per
// half), independent slot/E/X loads issued before FMAs.
__global__ __launch_bounds__(256) void edge_gather(const float* __restrict__ X,
                                                   const int* __restrict__ cnt,
                                                   const int* __restrict__ adjsrc,
                                                   const uint4* __restrict__ adjEb,
                                                   float* __restrict__ G) {
    int t = blockIdx.x * blockDim.x + threadIdx.x;
    int n = t >> 6;
    if (n >= N_NODES) return;
    int lane = t & 63;
    int i = lane & 31;
    int half = lane >> 5;

    int deg = min(cnt[n], DMAX);
    int base = n << 5;
    float g0 = 0.f, g1 = 0.f, g2 = 0.f, g3 = 0.f;
    float g4 = 0.f, g5 = 0.f, g6 = 0.f, g7 = 0.f, g8 = 0.f;

    int c = 0;
    for (; c + 8 <= deg; c += 8) {
        int k0 = base + c + half * 4;
        int s0 = adjsrc[k0 + 0];
        int s1 = adjsrc[k0 + 1];
        int s2 = adjsrc[k0 + 2];
        int s3 = adjsrc[k0 + 3];
        uint4 p0 = adjEb[k0 + 0];
        uint4 p1 = adjEb[k0 + 1];
        uint4 p2 = adjEb[k0 + 2];
        uint4 p3 = adjEb[k0 + 3];
        float xv0 = X[s0 * 32 + i];
        float xv1 = X[s1 * 32 + i];
        float xv2 = X[s2 * 32 + i];
        float xv3 = X[s3 * 32 + i];
        EDGE_FMA_P(p0, xv0);
        EDGE_FMA_P(p1, xv1);
        EDGE_FMA_P(p2, xv2);
        EDGE_FMA_P(p3, xv3);
    }
    for (int k = c + half; k < deg; k += 2) {
        int s = adjsrc[base + k];
        uint4 p = adjEb[base + k];
        float xv = X[s * 32 + i];
        EDGE_FMA_P(p, xv);
    }

    g0 += __shfl_xor(g0, 32); g1 += __shfl_xor(g1, 32);
    g2 += __shfl_xor(g2, 32); g3 += __shfl_xor(g3, 32);
    g4 += __shfl_xor(g4, 32); g5 += __shfl_xor(g5, 32);
    g6 += __shfl_xor(g6, 32); g7 += __shfl_xor(g7, 32);
    g8 += __shfl_xor(g8, 32);

    if (half == 0) {
        float* gr = G + (size_t)n * 288;
        gr[0 * 32 + i] = g0; gr[1 * 32 + i] = g1;
        gr[2 * 32 + i] = g2; gr[3 * 32 + i] = g3;
        gr[4 * 32 + i] = g4; gr[5 * 32 + i] = g5;
        gr[6 * 32 + i] = g6; gr[7 * 32 + i] = g7;
        gr[256 + i] = g8;
    }
}

// Epilogue GEMM, K-SPLIT x Mr=4 (R24): out[n][o] = sum_k Gext[n][k]*W'[k][o].
//   Gext = [G row (288) | X row (32)], W' = [knw|knb|root] verbatim in LDS.
// 256 thr/block = 4 waves; wave ks owns k4-slice [ks*20, ks*20+20) (k4<72 from
// G, else X). Lane = (mg = lane>>3, jg = lane&7); thread computes 4 nodes
// (mg*4..mg*4+3) x outs 4jg..4jg+3 partial sums. 625 blocks x 32 nodes (exact).
// Partials combined via 16KB LDS buffer; thread u reduces 4 slices + epilogue.
// -> 2500 waves (2.4/SIMD) with SAME total LDS-instr count as Mr=4.
// mode 0: H[n][o] = relu(out + bias[o]);  mode 1: util[n] = db + relu(.)@dw
__global__ __launch_bounds__(256) void epi_gemm(const float4* __restrict__ G4,
                                                const float4* __restrict__ X4,
                                                const float4* __restrict__ knw4,
                                                const float4* __restrict__ knb4,
                                                const float4* __restrict__ root4,
                                                const float* __restrict__ bias,
                                                const float* __restrict__ dw,
                                                const float* __restrict__ db,
                                                float* __restrict__ H,
                                                float* __restrict__ util,
                                                int mode) {
    __shared__ float Ws[320 * 32];     // 40,960 B
    __shared__ float4 parts[4 * 256];  // 16,384 B (total 57,344 -> 2 blocks/CU)
    int t = threadIdx.x;
    int nb = blockIdx.x * 32;

    // stage W' = [knw | knb | root] verbatim (2560 float4 / 256 thr = 10 each)
    {
        float4* d = (float4*)Ws;
#pragma unroll
        for (int c = 0; c < 10; ++c) {
            int idx = c * 256 + t;
            float4 v;
            if (idx < 2048) v = knw4[idx];
            else if (idx < 2304) v = knb4[idx - 2048];
            else v = root4[idx - 2304];
            d[idx] = v;
        }
    }
    __syncthreads();

    int ks = t >> 6;           // wave = K slice (0..3)
    int lane = t & 63;
    int mg = lane >> 3;        // node group (0..7) -> nodes mg*4..mg*4+3
    int jg = lane & 7;         // output quad
    int n0 = nb + mg * 4;

    float4 z = make_float4(0.f, 0.f, 0.f, 0.f);
    float4 a0 = z, a1 = z, a2 = z, a3 = z;

    for (int r = 0; r < 20; ++r) {
        int k4 = ks * 20 + r;  // wave-uniform
        float4 g0, g1, g2, g3;
        if (k4 < 72) {
            g0 = G4[(size_t)(n0 + 0) * 72 + k4];
            g1 = G4[(size_t)(n0 + 1) * 72 + k4];
            g2 = G4[(size_t)(n0 + 2) * 72 + k4];
            g3 = G4[(size_t)(n0 + 3) * 72 + k4];
        } else {
            int k8 = k4 - 72;
            g0 = X4[(size_t)(n0 + 0) * 8 + k8];
            g1 = X4[(size_t)(n0 + 1) * 8 + k8];
            g2 = X4[(size_t)(n0 + 2) * 8 + k8];
            g3 = X4[(size_t)(n0 + 3) * 8 + k8];
        }
        const float* wb = &Ws[(k4 * 4) * 32 + jg * 4];
        float4 w0 = *(const float4*)(wb);
        float4 w1 = *(const float4*)(wb + 32);
        float4 w2 = *(const float4*)(wb + 64);
        float4 w3 = *(const float4*)(wb + 96);
        a0 = f4fma(g0.x, w0, a0); a0 = f4fma(g0.y, w1, a0);
        a0 = f4fma(g0.z, w2, a0); a0 = f4fma(g0.w, w3, a0);
        a1 = f4fma(g1.x, w0, a1); a1 = f4fma(g1.y, w1, a1);
        a1 = f4fma(g1.z, w2, a1); a1 = f4fma(g1.w, w3, a1);
        a2 = f4fma(g2.x, w0, a2); a2 = f4fma(g2.y, w1, a2);
        a2 = f4fma(g2.z, w2, a2); a2 = f4fma(g2.w, w3, a2);
        a3 = f4fma(g3.x, w0, a3); a3 = f4fma(g3.y, w1, a3);
        a3 = f4fma(g3.z, w2, a3); a3 = f4fma(g3.w, w3, a3);
    }

    // deposit partials: parts[ks*256 + nl*8 + jg], nl = mg*4+m
    {
        int pb = ks * 256 + (mg * 4) * 8 + jg;
        parts[pb + 0 * 8] = a0;
        parts[pb + 1 * 8] = a1;
        parts[pb + 2 * 8] = a2;
        parts[pb + 3 * 8] = a3;
    }
    __syncthreads();

    // reduce: thread u -> (nl = u>>3, jg = u&7)
    int nl = t >> 3, jr = t & 7;
    float4 s0 = parts[0 * 256 + t];
    float4 s1 = parts[1 * 256 + t];
    float4 s2 = parts[2 * 256 + t];
    float4 s3 = parts[3 * 256 + t];
    float4 a;
    a.x = (s0.x + s1.x) + (s2.x + s3.x);
    a.y = (s0.y + s1.y) + (s2.y + s3.y);
    a.z = (s0.z + s1.z) + (s2.z + s3.z);
    a.w = (s0.w + s1.w) + (s2.w + s3.w);

    int n = nb + nl;
    float4 b = ((const float4*)bias)[jr];
    if (mode == 0) {
        float4 v;
        v.x = fmaxf(a.x + b.x, 0.f); v.y = fmaxf(a.y + b.y, 0.f);
        v.z = fmaxf(a.z + b.z, 0.f); v.w = fmaxf(a.w + b.w, 0.f);
        ((float4*)H)[n * 8 + jr] = v;
    } else {
        float4 dv = ((const float4*)dw)[jr];
        float p = fmaxf(a.x + b.x, 0.f) * dv.x + fmaxf(a.y + b.y, 0.f) * dv.y
                + fmaxf(a.z + b.z, 0.f) * dv.z + fmaxf(a.w + b.w, 0.f) * dv.w;
        p += __shfl_xor(p, 1);
        p += __shfl_xor(p, 2);
        p += __shfl_xor(p, 4);
        if (jr == 0) util[n] = p + db[0];
    }
}

// out[p] = util[idx_b[p]] - util[idx_a[p]]
__global__ void pair_kernel(const float* __restrict__ util, const int* __restrict__ ia,
                            const int* __restrict__ ib, float* __restrict__ out) {
    int p = blockIdx.x * blockDim.x + threadIdx.x;
    if (p >= N_PAIRS) return;
    out[p] = util[ib[p]] - util[ia[p]];
}

extern "C" void kernel_launch(void* const* d_in, const int* in_sizes, int n_in,
                              void* d_out, int out_size, void* d_ws, size_t ws_size,
                              hipStream_t stream) {
    const float* x     = (const float*)d_in[0];
    const float* e     = (const float*)d_in[1];
    const float* knw1  = (const float*)d_in[2];
    const float* knb1  = (const float*)d_in[3];
    const float* root1 = (const float*)d_in[4];
    const float* bias1 = (const float*)d_in[5];
    const float* knw2  = (const float*)d_in[6];
    const float* knb2  = (const float*)d_in[7];
    const float* root2 = (const float*)d_in[8];
    const float* bias2 = (const float*)d_in[9];
    const float* dw    = (const float*)d_in[10];
    const float* db    = (const float*)d_in[11];
    const int*   ei    = (const int*)d_in[12];
    const int*   ia    = (const int*)d_in[13];
    const int*   ib    = (const int*)d_in[14];
    float* out = (float*)d_out;

    float* ws = (float*)d_ws;
    float* G      = ws;                       // 20000*288 = 5,760,000 floats
    float* H      = ws + 5760000;             // 640,000
    float* util   = ws + 6400000;             // 20,000
    int*   cnt    = (int*)(ws + 6420000);     // 20,000
    int*   adjsrc = (int*)(ws + 6440000);     // 640,000 ints
    uint4* adjEb  = (uint4*)(ws + 7080000);   // 640,000 uint4 (16B-aligned)

    int nblk_epi = N_NODES / 32;                     // 625 (exact)
    int nblk_gat = (N_NODES * 64) / 256;             // 5000

    // ---- adjacency ----
    zero_cnt<<<(N_NODES + 255) / 256, 256, 0, stream>>>(cnt);
    fill_adj<<<(N_EDGES + 255) / 256, 256, 0, stream>>>(ei, e, cnt, adjsrc, adjEb);

    // ---- layer 1 ----
    edge_gather<<<nblk_gat, 256, 0, stream>>>(x, cnt, adjsrc, adjEb, G);
    epi_gemm<<<nblk_epi, 256, 0, stream>>>((const float4*)G, (const float4*)x,
                                           (const float4*)knw1, (const float4*)knb1,
                                           (const float4*)root1, bias1, dw, db,
                                           H, util, 0);
    // ---- layer 2 (+ readout) ----
    edge_gather<<<nblk_gat, 256, 0, stream>>>(H, cnt, adjsrc, adjEb, G);
    epi_gemm<<<nblk_epi, 256, 0, stream>>>((const float4*)G, (const float4*)H,
                                           (const float4*)knw2, (const float4*)knb2,
                                           (const float4*)root2, bias2, dw, db,
                                           H, util, 1);

    // ---- pairs ----
    pair_kernel<<<(N_PAIRS + 255) / 256, 256, 0, stream>>>(util, ia, ib, out);
}

// Round 26
// 82.258 us; speedup vs baseline: 1.4869x; 1.0109x over previous
//
#include <hip/hip_runtime.h>

#define N_NODES 20000
#define N_EDGES 160000
#define N_PAIRS 50000
#define DMAX 32
// F_IN = CHANNELS = 32, EDGE_DIM = 8; G row = 288 floats (knw 256 + knb 32)

__device__ __forceinline__ float4 f4fma(float s, float4 w, float4 a) {
    a.x += s * w.x; a.y += s * w.y; a.z += s * w.z; a.w += s * w.w;
    return a;
}

__device__ __forceinline__ float bf2f(unsigned int u) {  // low 16 bits = bf16
    return __uint_as_float(u << 16);
}
__device__ __forceinline__ unsigned int f2bf(float f) {  // RNE, low 16 bits
    unsigned int u = __float_as_uint(f);
    u += 0x7fffu + ((u >> 16) & 1u);
    return u >> 16;
}

__global__ void zero_cnt(int* __restrict__ c) {
    int t = blockIdx.x * blockDim.x + threadIdx.x;
    if (t < N_NODES) c[t] = 0;
}

// adjacency by target: slot -> src (int) + bf16-packed E row (uint4, 16B).
__global__ __launch_bounds__(256) void fill_adj(const int* __restrict__ ei,
                                                const float* __restrict__ E,
                                                int* __restrict__ cnt,
                                                int* __restrict__ adjsrc,
                                                uint4* __restrict__ adjEb) {
    int e = blockIdx.x * blockDim.x + threadIdx.x;
    if (e >= N_EDGES) return;
    int2 st = ((const int2*)ei)[e];  // x = src, y = tgt
    int slot = atomicAdd(&cnt[st.y], 1);
    if (slot < DMAX) {
        int idx = (st.y << 5) + slot;
        adjsrc[idx] = st.x;
        const float4* e4 = (const float4*)(E + (size_t)e * 8);
        float4 a = e4[0], b = e4[1];
        uint4 p;
        p.x = f2bf(a.x) | (f2bf(a.y) << 16);
        p.y = f2bf(a.z) | (f2bf(a.w) << 16);
        p.z = f2bf(b.x) | (f2bf(b.y) << 16);
        p.w = f2bf(b.z) | (f2bf(b.w) << 16);
        adjEb[idx] = p;
    }
}

#define EDGE_FMA_P(p, xv)                                                      \
    g0 += bf2f((p).x & 0xffffu) * (xv); g1 += bf2f((p).x >> 16) * (xv);        \
    g2 += bf2f((p).y & 0xffffu) * (xv); g3 += bf2f((p).y >> 16) * (xv);        \
    g4 += bf2f((p).z & 0xffffu) * (xv); g5 += bf2f((p).z >> 16) * (xv);        \
    g6 += bf2f((p).w & 0xffffu) * (xv); g7 += bf2f((p).w >> 16) * (xv);        \
    g8 += (xv);

// G gather (R14/R18-validated): ONE WAVE PER NODE; chunks of 8 edges (4 per
// half), independent slot/E/X loads issued before FMAs.
__global__ __launch_bounds__(256) void edge_gather(const float* __restrict__ X,
                                                   const int* __restrict__ cnt,
                                                   const int* __restrict__ adjsrc,
                                                   const uint4* __restrict__ adjEb,
                                                   float* __restrict__ G) {
    int t = blockIdx.x * blockDim.x + threadIdx.x;
    int n = t >> 6;
    if (n >= N_NODES) return;
    int lane = t & 63;
    int i = lane & 31;
    int half = lane >> 5;

    int deg = min(cnt[n], DMAX);
    int base = n << 5;
    float g0 = 0.f, g1 = 0.f, g2 = 0.f, g3 = 0.f;
    float g4 = 0.f, g5 = 0.f, g6 = 0.f, g7 = 0.f, g8 = 0.f;

    int c = 0;
    for (; c + 8 <= deg; c += 8) {
        int k0 = base + c + half * 4;
        int s0 = adjsrc[k0 + 0];
        int s1 = adjsrc[k0 + 1];
        int s2 = adjsrc[k0 + 2];
        int s3 = adjsrc[k0 + 3];
        uint4 p0 = adjEb[k0 + 0];
        uint4 p1 = adjEb[k0 + 1];
        uint4 p2 = adjEb[k0 + 2];
        uint4 p3 = adjEb[k0 + 3];
        float xv0 = X[s0 * 32 + i];
        float xv1 = X[s1 * 32 + i];
        float xv2 = X[s2 * 32 + i];
        float xv3 = X[s3 * 32 + i];
        EDGE_FMA_P(p0, xv0);
        EDGE_FMA_P(p1, xv1);
        EDGE_FMA_P(p2, xv2);
        EDGE_FMA_P(p3, xv3);
    }
    for (int k = c + half; k < deg; k += 2) {
        int s = adjsrc[base + k];
        uint4 p = adjEb[base + k];
        float xv = X[s * 32 + i];
        EDGE_FMA_P(p, xv);
    }

    g0 += __shfl_xor(g0, 32); g1 += __shfl_xor(g1, 32);
    g2 += __shfl_xor(g2, 32); g3 += __shfl_xor(g3, 32);
    g4 += __shfl_xor(g4, 32); g5 += __shfl_xor(g5, 32);
    g6 += __shfl_xor(g6, 32); g7 += __shfl_xor(g7, 32);
    g8 += __shfl_xor(g8, 32);

    if (half == 0) {
        float* gr = G + (size_t)n * 288;
        gr[0 * 32 + i] = g0; gr[1 * 32 + i] = g1;
        gr[2 * 32 + i] = g2; gr[3 * 32 + i] = g3;
        gr[4 * 32 + i] = g4; gr[5 * 32 + i] = g5;
        gr[6 * 32 + i] = g6; gr[7 * 32 + i] = g7;
        gr[256 + i] = g8;
    }
}

// Epilogue GEMM, K-SPLIT x Mr=4 + bf16 W' in LDS (R25).
//   out[n][o] = sum_k Gext[n][k]*W'[k][o]; Gext = [G row (288) | X row (32)].
// W' packed bf16 in LDS (20,480B); + parts (16,384B) = 36,864B -> 4 blocks/CU
// (16 waves/CU, 2x R24) to hide the scattered G-load latency.
// 256 thr/block = 4 waves; wave ks owns k4-slice [ks*20, ks*20+20); thread
// (mg, jg) computes nodes mg*4..+3 x outs 4jg..+3 partials; LDS reduce.
// 625 blocks x 32 nodes (exact).
__global__ __launch_bounds__(256) void epi_gemm(const float4* __restrict__ G4,
                                                const float4* __restrict__ X4,
                                                const float4* __restrict__ knw4,
                                                const float4* __restrict__ knb4,
                                                const float4* __restrict__ root4,
                                                const float* __restrict__ bias,
                                                const float* __restrict__ dw,
                                                const float* __restrict__ db,
                                                float* __restrict__ H,
                                                float* __restrict__ util,
                                                int mode) {
    __shared__ unsigned int WsB[320 * 16];  // bf16-packed W': 20,480 B
    __shared__ float4 parts[4 * 256];       // 16,384 B
    int t = threadIdx.x;
    int nb = blockIdx.x * 32;

    // stage W' = [knw | knb | root] verbatim, packed to bf16 pairs along o.
    // global float4 idx: k = idx>>3, o4 = idx&7 -> WsB[k*16 + o4*2 (+1)]
    {
#pragma unroll
        for (int c = 0; c < 10; ++c) {
            int idx = c * 256 + t;
            float4 v;
            if (idx < 2048) v = knw4[idx];
            else if (idx < 2304) v = knb4[idx - 2048];
            else v = root4[idx - 2304];
            int k = idx >> 3, o4 = idx & 7;
            WsB[k * 16 + o4 * 2 + 0] = f2bf(v.x) | (f2bf(v.y) << 16);
            WsB[k * 16 + o4 * 2 + 1] = f2bf(v.z) | (f2bf(v.w) << 16);
        }
    }
    __syncthreads();

    int ks = t >> 6;           // wave = K slice (0..3)
    int lane = t & 63;
    int mg = lane >> 3;        // node group (0..7) -> nodes mg*4..mg*4+3
    int jg = lane & 7;         // output quad
    int n0 = nb + mg * 4;

    float4 z = make_float4(0.f, 0.f, 0.f, 0.f);
    float4 a0 = z, a1 = z, a2 = z, a3 = z;

    for (int r = 0; r < 20; ++r) {
        int k4 = ks * 20 + r;  // wave-uniform
        float4 g0, g1, g2, g3;
        if (k4 < 72) {
            g0 = G4[(size_t)(n0 + 0) * 72 + k4];
            g1 = G4[(size_t)(n0 + 1) * 72 + k4];
            g2 = G4[(size_t)(n0 + 2) * 72 + k4];
            g3 = G4[(size_t)(n0 + 3) * 72 + k4];
        } else {
            int k8 = k4 - 72;
            g0 = X4[(size_t)(n0 + 0) * 8 + k8];
            g1 = X4[(size_t)(n0 + 1) * 8 + k8];
            g2 = X4[(size_t)(n0 + 2) * 8 + k8];
            g3 = X4[(size_t)(n0 + 3) * 8 + k8];
        }
#pragma unroll
        for (int kk = 0; kk < 4; ++kk) {
            uint2 wq = *(const uint2*)&WsB[(k4 * 4 + kk) * 16 + jg * 2];
            float4 w;
            w.x = bf2f(wq.x & 0xffffu); w.y = bf2f(wq.x >> 16);
            w.z = bf2f(wq.y & 0xffffu); w.w = bf2f(wq.y >> 16);
            float s0 = (kk == 0) ? g0.x : (kk == 1) ? g0.y : (kk == 2) ? g0.z : g0.w;
            float s1 = (kk == 0) ? g1.x : (kk == 1) ? g1.y : (kk == 2) ? g1.z : g1.w;
            float s2 = (kk == 0) ? g2.x : (kk == 1) ? g2.y : (kk == 2) ? g2.z : g2.w;
            float s3 = (kk == 0) ? g3.x : (kk == 1) ? g3.y : (kk == 2) ? g3.z : g3.w;
            a0 = f4fma(s0, w, a0);
            a1 = f4fma(s1, w, a1);
            a2 = f4fma(s2, w, a2);
            a3 = f4fma(s3, w, a3);
        }
    }

    // deposit partials: parts[ks*256 + nl*8 + jg], nl = mg*4+m
    {
        int pb = ks * 256 + (mg * 4) * 8 + jg;
        parts[pb + 0 * 8] = a0;
        parts[pb + 1 * 8] = a1;
        parts[pb + 2 * 8] = a2;
        parts[pb + 3 * 8] = a3;
    }
    __syncthreads();

    // reduce: thread u -> (nl = u>>3, jr = u&7)
    int nl = t >> 3, jr = t & 7;
    float4 s0 = parts[0 * 256 + t];
    float4 s1 = parts[1 * 256 + t];
    float4 s2 = parts[2 * 256 + t];
    float4 s3 = parts[3 * 256 + t];
    float4 a;
    a.x = (s0.x + s1.x) + (s2.x + s3.x);
    a.y = (s0.y + s1.y) + (s2.y + s3.y);
    a.z = (s0.z + s1.z) + (s2.z + s3.z);
    a.w = (s0.w + s1.w) + (s2.w + s3.w);

    int n = nb + nl;
    float4 b = ((const float4*)bias)[jr];
    if (mode == 0) {
        float4 v;
        v.x = fmaxf(a.x + b.x, 0.f); v.y = fmaxf(a.y + b.y, 0.f);
        v.z = fmaxf(a.z + b.z, 0.f); v.w = fmaxf(a.w + b.w, 0.f);
        ((float4*)H)[n * 8 + jr] = v;
    } else {
        float4 dv = ((const float4*)dw)[jr];
        float p = fmaxf(a.x + b.x, 0.f) * dv.x + fmaxf(a.y + b.y, 0.f) * dv.y
                + fmaxf(a.z + b.z, 0.f) * dv.z + fmaxf(a.w + b.w, 0.f) * dv.w;
        p += __shfl_xor(p, 1);
        p += __shfl_xor(p, 2);
        p += __shfl_xor(p, 4);
        if (jr == 0) util[n] = p + db[0];
    }
}

// out[p] = util[idx_b[p]] - util[idx_a[p]]
__global__ void pair_kernel(const float* __restrict__ util, const int* __restrict__ ia,
                            const int* __restrict__ ib, float* __restrict__ out) {
    int p = blockIdx.x * blockDim.x + threadIdx.x;
    if (p >= N_PAIRS) return;
    out[p] = util[ib[p]] - util[ia[p]];
}

extern "C" void kernel_launch(void* const* d_in, const int* in_sizes, int n_in,
                              void* d_out, int out_size, void* d_ws, size_t ws_size,
                              hipStream_t stream) {
    const float* x     = (const float*)d_in[0];
    const float* e     = (const float*)d_in[1];
    const float* knw1  = (const float*)d_in[2];
    const float* knb1  = (const float*)d_in[3];
    const float* root1 = (const float*)d_in[4];
    const float* bias1 = (const float*)d_in[5];
    const float* knw2  = (const float*)d_in[6];
    const float* knb2  = (const float*)d_in[7];
    const float* root2 = (const float*)d_in[8];
    const float* bias2 = (const float*)d_in[9];
    const float* dw    = (const float*)d_in[10];
    const float* db    = (const float*)d_in[11];
    const int*   ei    = (const int*)d_in[12];
    const int*   ia    = (const int*)d_in[13];
    const int*   ib    = (const int*)d_in[14];
    float* out = (float*)d_out;

    float* ws = (float*)d_ws;
    float* G      = ws;                       // 20000*288 = 5,760,000 floats
    float* H      = ws + 5760000;             // 640,000
    float* util   = ws + 6400000;             // 20,000
    int*   cnt    = (int*)(ws + 6420000);     // 20,000
    int*   adjsrc = (int*)(ws + 6440000);     // 640,000 ints
    uint4* adjEb  = (uint4*)(ws + 7080000);   // 640,000 uint4 (16B-aligned)

    int nblk_epi = N_NODES / 32;                     // 625 (exact)
    int nblk_gat = (N_NODES * 64) / 256;             // 5000

    // ---- adjacency ----
    zero_cnt<<<(N_NODES + 255) / 256, 256, 0, stream>>>(cnt);
    fill_adj<<<(N_EDGES + 255) / 256, 256, 0, stream>>>(ei, e, cnt, adjsrc, adjEb);

    // ---- layer 1 ----
    edge_gather<<<nblk_gat, 256, 0, stream>>>(x, cnt, adjsrc, adjEb, G);
    epi_gemm<<<nblk_epi, 256, 0, stream>>>((const float4*)G, (const float4*)x,
                                           (const float4*)knw1, (const float4*)knb1,
                                           (const float4*)root1, bias1, dw, db,
                                           H, util, 0);
    // ---- layer 2 (+ readout) ----
    edge_gather<<<nblk_gat, 256, 0, stream>>>(H, cnt, adjsrc, adjEb, G);
    epi_gemm<<<nblk_epi, 256, 0, stream>>>((const float4*)G, (const float4*)H,
                                           (const float4*)knw2, (const float4*)knb2,
                                           (const float4*)root2, bias2, dw, db,
                                           H, util, 1);

    // ---- pairs ----
    pair_kernel<<<(N_PAIRS + 255) / 256, 256, 0, stream>>>(util, ia, ib, out);
}